// Round 4
// baseline (195.162 us; speedup 1.0000x reference)
//
#include <hip/hip_runtime.h>
#include <math.h>

#define Bb 2
#define Ll 2048
#define Dm 1024
#define Ns 16
#define Rr 64
#define Ee 96          // DT_RANK + 2*D_STATE
#define CH 128         // chunks
#define CL 16          // chunk length = Ll / CH
#define XPS 16         // K-splits for xproj GEMM (K-slice = 64)
#define BLK (Bb*Ll)    // 4096 rows
#define NTHR 256

// ========== Kernel 1: xp_part[ks][bl][e] = sum_{k in slice} x[bl][k]*xw[e][k] ==========
// 64 mtiles (BM=64) x 16 ksplits = 1024 blocks. K-slice 64, staged in 2 sub-chunks of 32.
__global__ void __launch_bounds__(NTHR)
k_xproj(const float* __restrict__ x, const float* __restrict__ xw,
        float* __restrict__ xp_part) {
    __shared__ float xs[64 * 37];
    __shared__ float wsh[96 * 37];
    int bx = blockIdx.x;
    int ks = bx & 15, mt = bx >> 4;
    int i0 = mt * 64;
    int tid = threadIdx.x;
    int tx = tid & 15, ty = tid >> 4;      // tile 4(i) x 6(j)
    float acc[4][6];
#pragma unroll
    for (int ii = 0; ii < 4; ++ii)
#pragma unroll
        for (int jj = 0; jj < 6; ++jj) acc[ii][jj] = 0.f;

    for (int kc = 0; kc < 2; ++kc) {
        int k0 = ks * 64 + kc * 32;
        for (int t = tid; t < 512; t += NTHR) {          // x: 64 rows x 32 k
            int r = t >> 3, c = (t & 7) * 4;
            float4 v = *(const float4*)(x + (size_t)(i0 + r) * Dm + k0 + c);
            xs[r*37+c] = v.x; xs[r*37+c+1] = v.y; xs[r*37+c+2] = v.z; xs[r*37+c+3] = v.w;
        }
        for (int t = tid; t < 768; t += NTHR) {          // w: 96 rows x 32 k
            int r = t >> 3, c = (t & 7) * 4;
            float4 v = *(const float4*)(xw + (size_t)r * Dm + k0 + c);
            wsh[r*37+c] = v.x; wsh[r*37+c+1] = v.y; wsh[r*37+c+2] = v.z; wsh[r*37+c+3] = v.w;
        }
        __syncthreads();
#pragma unroll 8
        for (int k = 0; k < 32; ++k) {
            float xv[4], wv[6];
#pragma unroll
            for (int ii = 0; ii < 4; ++ii) xv[ii] = xs[(ty*4+ii)*37 + k];
#pragma unroll
            for (int jj = 0; jj < 6; ++jj) wv[jj] = wsh[(tx*6+jj)*37 + k];
#pragma unroll
            for (int ii = 0; ii < 4; ++ii)
#pragma unroll
                for (int jj = 0; jj < 6; ++jj)
                    acc[ii][jj] = fmaf(xv[ii], wv[jj], acc[ii][jj]);
        }
        __syncthreads();
    }
#pragma unroll
    for (int ii = 0; ii < 4; ++ii)
#pragma unroll
        for (int jj = 0; jj < 6; ++jj)
            xp_part[((size_t)ks * BLK + (i0 + ty*4 + ii)) * Ee + tx*6 + jj] = acc[ii][jj];
}

// ========== Kernel 2: reduce K-splits -> xp ; transpose dtw -> dtwT[k][d] ==========
__global__ void __launch_bounds__(NTHR)
k_prep(const float* __restrict__ xp_part, float* __restrict__ xp,
       const float* __restrict__ dtw, float* __restrict__ dtwT) {
    int nthr = gridDim.x * NTHR;
    int gid0 = blockIdx.x * NTHR + threadIdx.x;
    for (int g = gid0; g < BLK * Ee; g += nthr) {
        float s = 0.f;
#pragma unroll
        for (int i = 0; i < XPS; ++i) s += xp_part[(size_t)i * (BLK * Ee) + g];
        xp[g] = s;
    }
    for (int g = gid0; g < Dm * Rr; g += nthr) {
        int d = g >> 6, k = g & 63;           // read coalesced over k
        dtwT[k * Dm + d] = dtw[g];
    }
}

// ========== fused delta-GEMM + scan body helpers ==========
// Stage this chunk's xp rows [16][96] into LDS (stride 97).
__device__ inline void stage_xp(float* xs, int tid, const float* __restrict__ xp, int row0) {
    for (int t = tid; t < 16 * 24; t += NTHR) {
        int r = t / 24, c = (t % 24) * 4;
        float4 v = *(const float4*)(xp + (size_t)(row0 + r) * Ee + c);
        xs[r*97+c] = v.x; xs[r*97+c+1] = v.y; xs[r*97+c+2] = v.z; xs[r*97+c+3] = v.w;
    }
}

// Per-thread delta for 16 timesteps of this chunk (k-loop over dtwT, LDS-broadcast xs).
__device__ inline void compute_delta(const float* xs, int d, const float* __restrict__ dtwT,
                                     const float* __restrict__ dtb, float* dl) {
    float acc[CL];
#pragma unroll
    for (int t = 0; t < CL; ++t) acc[t] = 0.f;
#pragma unroll 4
    for (int k = 0; k < Rr; ++k) {
        float w = dtwT[(size_t)k * Dm + d];
#pragma unroll
        for (int t = 0; t < CL; ++t)
            acc[t] = fmaf(xs[t*97 + k], w, acc[t]);
    }
    float bias = dtb[d];
#pragma unroll
    for (int t = 0; t < CL; ++t) {
        float z = acc[t] + bias;
        dl[t] = fmaxf(z, 0.f) + log1pf(__expf(-fabsf(z)));
    }
}

// ========== Kernel 3: per-chunk local scan (h0=0) -> Ec, Sc ==========
__global__ void __launch_bounds__(NTHR, 4)
k_scan_part(const float* __restrict__ x, const float* __restrict__ xp,
            const float* __restrict__ dtwT, const float* __restrict__ dtb,
            const float* __restrict__ A_log,
            float* __restrict__ Ec, float* __restrict__ Sc) {
    __shared__ float xs[16 * 97];
    int bx = blockIdx.x;
    int dblk = bx & 3, chunk = (bx >> 2) & (CH - 1), b = bx >> 9;
    int tid = threadIdx.x;
    int d = dblk * 256 + tid;
    int row0 = b * Ll + chunk * CL;

    stage_xp(xs, tid, xp, row0);
    __syncthreads();

    float dl[CL];
    compute_delta(xs, d, dtwT, dtb, dl);

    float a[Ns], h[Ns];
    {
        const float4* Ap = (const float4*)(A_log + (size_t)d * Ns);
        float4 a0 = Ap[0], a1 = Ap[1], a2 = Ap[2], a3 = Ap[3];
        float tmp[Ns] = {a0.x,a0.y,a0.z,a0.w, a1.x,a1.y,a1.z,a1.w,
                         a2.x,a2.y,a2.z,a2.w, a3.x,a3.y,a3.z,a3.w};
#pragma unroll
        for (int n = 0; n < Ns; ++n) { a[n] = -__expf(tmp[n]); h[n] = 0.f; }
    }
    float sd = 0.f;
#pragma unroll
    for (int t = 0; t < CL; ++t) {
        float xv = x[(size_t)(row0 + t) * Dm + d];
        float dx = dl[t] * xv;
        sd += dl[t];
#pragma unroll
        for (int n = 0; n < Ns; ++n)
            h[n] = __expf(dl[t] * a[n]) * h[n] + dx * xs[t*97 + Rr + n];
    }
    size_t base = ((size_t)b * CH + chunk) * Dm + d;
    float4* Ep = (float4*)(Ec + base * Ns);
    Ep[0] = make_float4(h[0],  h[1],  h[2],  h[3]);
    Ep[1] = make_float4(h[4],  h[5],  h[6],  h[7]);
    Ep[2] = make_float4(h[8],  h[9],  h[10], h[11]);
    Ep[3] = make_float4(h[12], h[13], h[14], h[15]);
    Sc[base] = sd;
}

// ========== Kernel 4: sequential combine over chunks -> Hin ==========
__global__ void __launch_bounds__(NTHR)
k_combine(const float* __restrict__ Ec, const float* __restrict__ Sc,
          const float* __restrict__ A_log, float* __restrict__ Hin) {
    int gid = blockIdx.x * NTHR + threadIdx.x;   // < Bb*Dm*Ns = 32768
    int n = gid & (Ns - 1);
    int d = (gid >> 4) & (Dm - 1);
    int b = gid >> 14;
    float a = -__expf(A_log[d * Ns + n]);
    float h = 0.f;
    for (int c = 0; c < CH; ++c) {
        size_t base = ((size_t)b * CH + c) * Dm + d;
        Hin[base * Ns + n] = h;
        float P = __expf(a * Sc[base]);
        h = P * h + Ec[base * Ns + n];
    }
}

// ========== Kernel 5: full scan from true h_in, emit y ==========
__global__ void __launch_bounds__(NTHR, 4)
k_scan_full(const float* __restrict__ x, const float* __restrict__ xp,
            const float* __restrict__ dtwT, const float* __restrict__ dtb,
            const float* __restrict__ A_log, const float* __restrict__ Dp,
            const float* __restrict__ Hin, float* __restrict__ out) {
    __shared__ float xs[16 * 97];
    int bx = blockIdx.x;
    int dblk = bx & 3, chunk = (bx >> 2) & (CH - 1), b = bx >> 9;
    int tid = threadIdx.x;
    int d = dblk * 256 + tid;
    int row0 = b * Ll + chunk * CL;

    stage_xp(xs, tid, xp, row0);
    __syncthreads();

    float dl[CL];
    compute_delta(xs, d, dtwT, dtb, dl);

    float a[Ns], h[Ns];
    {
        const float4* Ap = (const float4*)(A_log + (size_t)d * Ns);
        float4 a0 = Ap[0], a1 = Ap[1], a2 = Ap[2], a3 = Ap[3];
        float tmp[Ns] = {a0.x,a0.y,a0.z,a0.w, a1.x,a1.y,a1.z,a1.w,
                         a2.x,a2.y,a2.z,a2.w, a3.x,a3.y,a3.z,a3.w};
#pragma unroll
        for (int n = 0; n < Ns; ++n) a[n] = -__expf(tmp[n]);
    }
    size_t base = ((size_t)b * CH + chunk) * Dm + d;
    {
        const float4* Hp = (const float4*)(Hin + base * Ns);
        float4 h0 = Hp[0], h1 = Hp[1], h2 = Hp[2], h3 = Hp[3];
        h[0]=h0.x; h[1]=h0.y; h[2]=h0.z; h[3]=h0.w;
        h[4]=h1.x; h[5]=h1.y; h[6]=h1.z; h[7]=h1.w;
        h[8]=h2.x; h[9]=h2.y; h[10]=h2.z; h[11]=h2.w;
        h[12]=h3.x; h[13]=h3.y; h[14]=h3.z; h[15]=h3.w;
    }
    float Dval = Dp[d];
#pragma unroll
    for (int t = 0; t < CL; ++t) {
        float xv = x[(size_t)(row0 + t) * Dm + d];
        float dx = dl[t] * xv;
        float y = 0.f;
#pragma unroll
        for (int n = 0; n < Ns; ++n) {
            h[n] = __expf(dl[t] * a[n]) * h[n] + dx * xs[t*97 + Rr + n];
            y += h[n] * xs[t*97 + Rr + Ns + n];
        }
        out[(size_t)(row0 + t) * Dm + d] = y + xv * Dval;
    }
}

extern "C" void kernel_launch(void* const* d_in, const int* in_sizes, int n_in,
                              void* d_out, int out_size, void* d_ws, size_t ws_size,
                              hipStream_t stream) {
    const float* x     = (const float*)d_in[0];
    const float* A_log = (const float*)d_in[1];
    const float* Dp    = (const float*)d_in[2];
    const float* xw    = (const float*)d_in[3];
    const float* dtw   = (const float*)d_in[4];
    const float* dtb   = (const float*)d_in[5];
    float* out = (float*)d_out;
    float* ws  = (float*)d_ws;

    // layout (floats):
    //   xp   : 393216
    //   dtwT : 65536
    //   S3 region (aliased):
    //     phase 1: xp_part = 16 * 393216 = 6291456   [dead after k_prep]
    //     phase 3+: Ec (4194304) | Sc (262144) | Hin (4194304) = 8650752
    float* xp      = ws;
    float* dtwT    = xp + 393216;
    float* S3      = dtwT + 65536;
    float* xp_part = S3;
    float* Ec      = S3;
    float* Sc      = Ec + 4194304;
    float* Hin     = Sc + 262144;
    // total = 393216 + 65536 + 8650752 = 9,109,504 floats = 36.4 MB

    k_xproj    <<<dim3(1024), dim3(NTHR), 0, stream>>>(x, xw, xp_part);
    k_prep     <<<dim3(512),  dim3(NTHR), 0, stream>>>(xp_part, xp, dtw, dtwT);
    k_scan_part<<<dim3(1024), dim3(NTHR), 0, stream>>>(x, xp, dtwT, dtb, A_log, Ec, Sc);
    k_combine  <<<dim3(128),  dim3(NTHR), 0, stream>>>(Ec, Sc, A_log, Hin);
    k_scan_full<<<dim3(1024), dim3(NTHR), 0, stream>>>(x, xp, dtwT, dtb, A_log, Dp, Hin, out);
}

// Round 5
// 165.403 us; speedup vs baseline: 1.1799x; 1.1799x over previous
//
#include <hip/hip_runtime.h>
#include <math.h>

#define Bb 2
#define Ll 2048
#define Dm 1024
#define Ns 16
#define Rr 64
#define Ee 96          // DT_RANK + 2*D_STATE
#define XPS 8          // K-splits for xproj GEMM (K-slice = 128)
#define BLK (Bb*Ll)    // 4096 rows
#define NTHR 256

// ========== Kernel 1: xp_part[ks][bl][e] = sum_{k in slice} x[bl][k]*xw[e][k] ==========
// 64 mtiles (BM=64) x 8 ksplits = 512 blocks. K-slice 128, staged in 4 sub-chunks of 32.
__global__ void __launch_bounds__(NTHR)
k_xproj(const float* __restrict__ x, const float* __restrict__ xw,
        float* __restrict__ xp_part) {
    __shared__ float xs[64 * 37];
    __shared__ float wsh[96 * 37];
    int bx = blockIdx.x;
    int ks = bx & 7, mt = bx >> 3;
    int i0 = mt * 64;
    int tid = threadIdx.x;
    int tx = tid & 15, ty = tid >> 4;      // tile 4(i) x 6(j)
    float acc[4][6];
#pragma unroll
    for (int ii = 0; ii < 4; ++ii)
#pragma unroll
        for (int jj = 0; jj < 6; ++jj) acc[ii][jj] = 0.f;

    for (int kc = 0; kc < 4; ++kc) {
        int k0 = ks * 128 + kc * 32;
        for (int t = tid; t < 512; t += NTHR) {          // x: 64 rows x 32 k
            int r = t >> 3, c = (t & 7) * 4;
            float4 v = *(const float4*)(x + (size_t)(i0 + r) * Dm + k0 + c);
            xs[r*37+c] = v.x; xs[r*37+c+1] = v.y; xs[r*37+c+2] = v.z; xs[r*37+c+3] = v.w;
        }
        for (int t = tid; t < 768; t += NTHR) {          // w: 96 rows x 32 k
            int r = t >> 3, c = (t & 7) * 4;
            float4 v = *(const float4*)(xw + (size_t)r * Dm + k0 + c);
            wsh[r*37+c] = v.x; wsh[r*37+c+1] = v.y; wsh[r*37+c+2] = v.z; wsh[r*37+c+3] = v.w;
        }
        __syncthreads();
#pragma unroll 8
        for (int k = 0; k < 32; ++k) {
            float xv[4], wv[6];
#pragma unroll
            for (int ii = 0; ii < 4; ++ii) xv[ii] = xs[(ty*4+ii)*37 + k];
#pragma unroll
            for (int jj = 0; jj < 6; ++jj) wv[jj] = wsh[(tx*6+jj)*37 + k];
#pragma unroll
            for (int ii = 0; ii < 4; ++ii)
#pragma unroll
                for (int jj = 0; jj < 6; ++jj)
                    acc[ii][jj] = fmaf(xv[ii], wv[jj], acc[ii][jj]);
        }
        __syncthreads();
    }
#pragma unroll
    for (int ii = 0; ii < 4; ++ii)
#pragma unroll
        for (int jj = 0; jj < 6; ++jj)
            xp_part[((size_t)ks * BLK + (i0 + ty*4 + ii)) * Ee + tx*6 + jj] = acc[ii][jj];
}

// ========== Kernel 2: reduce K-splits -> xp (float4 grid-exact) ==========
__global__ void __launch_bounds__(NTHR)
k_prep(const float* __restrict__ xp_part, float* __restrict__ xp) {
    int g = blockIdx.x * NTHR + threadIdx.x;    // 98304 float4s
    const float4* p = (const float4*)xp_part;
    float4 s = p[g];
#pragma unroll
    for (int i = 1; i < XPS; ++i) {
        float4 v = p[(size_t)i * (BLK * Ee / 4) + g];
        s.x += v.x; s.y += v.y; s.z += v.z; s.w += v.w;
    }
    ((float4*)xp)[g] = s;
}

// ========== Kernel 3: delta[bl][d] = softplus(xp[bl][:64] . dtw[d] + dtb[d]) ==========
// M=4096 N=1024 K=64. BM=64, BN=64 -> 64x16 = 1024 blocks. Thread tile 4x4.
__global__ void __launch_bounds__(NTHR)
k_delta(const float* __restrict__ xp, const float* __restrict__ dtw,
        const float* __restrict__ dtb, float* __restrict__ delta) {
    __shared__ float xs[64 * 65];
    __shared__ float wsh[64 * 65];
    int bx = blockIdx.x;
    int nt = bx & 15, mt = bx >> 4;
    int i0 = mt * 64, j0 = nt * 64;
    int tid = threadIdx.x, tx = tid & 15, ty = tid >> 4;

    for (int t = tid; t < 1024; t += NTHR) {
        int r = t >> 4, c = (t & 15) * 4;
        float4 v = *(const float4*)(xp + (size_t)(i0 + r) * Ee + c);
        xs[r*65+c] = v.x; xs[r*65+c+1] = v.y; xs[r*65+c+2] = v.z; xs[r*65+c+3] = v.w;
        float4 w = *(const float4*)(dtw + (size_t)(j0 + r) * Rr + c);
        wsh[r*65+c] = w.x; wsh[r*65+c+1] = w.y; wsh[r*65+c+2] = w.z; wsh[r*65+c+3] = w.w;
    }
    __syncthreads();

    float acc[4][4];
#pragma unroll
    for (int ii = 0; ii < 4; ++ii)
#pragma unroll
        for (int jj = 0; jj < 4; ++jj) acc[ii][jj] = 0.f;
#pragma unroll 8
    for (int k = 0; k < 64; ++k) {
        float xv[4], wv[4];
#pragma unroll
        for (int ii = 0; ii < 4; ++ii) xv[ii] = xs[(ty*4+ii)*65 + k];
#pragma unroll
        for (int jj = 0; jj < 4; ++jj) wv[jj] = wsh[(tx*4+jj)*65 + k];
#pragma unroll
        for (int ii = 0; ii < 4; ++ii)
#pragma unroll
            for (int jj = 0; jj < 4; ++jj)
                acc[ii][jj] = fmaf(xv[ii], wv[jj], acc[ii][jj]);
    }
    int d0 = j0 + tx * 4;
    float4 bias = *(const float4*)(dtb + d0);
#pragma unroll
    for (int ii = 0; ii < 4; ++ii) {
        int bl = i0 + ty*4 + ii;
        float z0 = acc[ii][0] + bias.x, z1 = acc[ii][1] + bias.y;
        float z2 = acc[ii][2] + bias.z, z3 = acc[ii][3] + bias.w;
        float4 o;
        o.x = fmaxf(z0, 0.f) + log1pf(__expf(-fabsf(z0)));
        o.y = fmaxf(z1, 0.f) + log1pf(__expf(-fabsf(z1)));
        o.z = fmaxf(z2, 0.f) + log1pf(__expf(-fabsf(z2)));
        o.w = fmaxf(z3, 0.f) + log1pf(__expf(-fabsf(z3)));
        *(float4*)(delta + (size_t)bl * Dm + d0) = o;
    }
}

// ---- helper: load A row into regs ----
__device__ inline void load_a(const float* __restrict__ A_log, int d, float* a) {
    const float4* Ap = (const float4*)(A_log + (size_t)d * Ns);
    float4 a0 = Ap[0], a1 = Ap[1], a2 = Ap[2], a3 = Ap[3];
    float tmp[Ns] = {a0.x,a0.y,a0.z,a0.w, a1.x,a1.y,a1.z,a1.w,
                     a2.x,a2.y,a2.z,a2.w, a3.x,a3.y,a3.z,a3.w};
#pragma unroll
    for (int n = 0; n < Ns; ++n) a[n] = -__expf(tmp[n]);
}

// ========== Kernel 4: per-chunk local scan (h0=0) -> Ec, Sc.  NO LDS. ==========
// grid = Bb * CHv * 4 blocks of 256. B-row reads are block-uniform -> scalar loads.
template<int CHv>
__global__ void __launch_bounds__(NTHR)
k_scan_part(const float* __restrict__ delta, const float* __restrict__ x,
            const float* __restrict__ xp, const float* __restrict__ A_log,
            float* __restrict__ Ec, float* __restrict__ Sc) {
    constexpr int CLv = Ll / CHv;
    int bx = blockIdx.x;
    int dblk = bx & 3, chunk = (bx >> 2) & (CHv - 1), b = bx >> 2 >> __builtin_ctz(CHv);
    int tid = threadIdx.x;
    int d = dblk * 256 + tid;
    int row0 = b * Ll + chunk * CLv;

    float a[Ns], h[Ns];
    load_a(A_log, d, a);
#pragma unroll
    for (int n = 0; n < Ns; ++n) h[n] = 0.f;
    float sd = 0.f;

#pragma unroll 4
    for (int t = 0; t < CLv; ++t) {
        size_t row = (size_t)(row0 + t);
        float dl = delta[row * Dm + d];
        float xv = x[row * Dm + d];
        // block-uniform B row -> scalar loads
        const float* bp = xp + row * Ee + Rr;
        float4 B0 = *(const float4*)(bp + 0),  B1 = *(const float4*)(bp + 4);
        float4 B2 = *(const float4*)(bp + 8),  B3 = *(const float4*)(bp + 12);
        float Bv[Ns] = {B0.x,B0.y,B0.z,B0.w, B1.x,B1.y,B1.z,B1.w,
                        B2.x,B2.y,B2.z,B2.w, B3.x,B3.y,B3.z,B3.w};
        float dx = dl * xv;
        sd += dl;
#pragma unroll
        for (int n = 0; n < Ns; ++n)
            h[n] = fmaf(__expf(dl * a[n]), h[n], dx * Bv[n]);
    }
    size_t base = ((size_t)b * CHv + chunk) * Dm + d;
    float4* Ep = (float4*)(Ec + base * Ns);
    Ep[0] = make_float4(h[0],  h[1],  h[2],  h[3]);
    Ep[1] = make_float4(h[4],  h[5],  h[6],  h[7]);
    Ep[2] = make_float4(h[8],  h[9],  h[10], h[11]);
    Ep[3] = make_float4(h[12], h[13], h[14], h[15]);
    Sc[base] = sd;
}

// ========== Kernel 5: sequential combine over chunks -> Hin ==========
template<int CHv>
__global__ void __launch_bounds__(NTHR)
k_combine(const float* __restrict__ Ec, const float* __restrict__ Sc,
          const float* __restrict__ A_log, float* __restrict__ Hin) {
    int gid = blockIdx.x * NTHR + threadIdx.x;   // < Bb*Dm*Ns = 32768
    int n = gid & (Ns - 1);
    int d = (gid >> 4) & (Dm - 1);
    int b = gid >> 14;
    float a = -__expf(A_log[d * Ns + n]);
    float h = 0.f;
    for (int c = 0; c < CHv; ++c) {
        size_t base = ((size_t)b * CHv + c) * Dm + d;
        Hin[base * Ns + n] = h;
        float P = __expf(a * Sc[base]);
        h = fmaf(P, h, Ec[base * Ns + n]);
    }
}

// ========== Kernel 6: full scan from true h_in, emit y.  NO LDS. ==========
template<int CHv>
__global__ void __launch_bounds__(NTHR)
k_scan_full(const float* __restrict__ delta, const float* __restrict__ x,
            const float* __restrict__ xp, const float* __restrict__ A_log,
            const float* __restrict__ Dp, const float* __restrict__ Hin,
            float* __restrict__ out) {
    constexpr int CLv = Ll / CHv;
    int bx = blockIdx.x;
    int dblk = bx & 3, chunk = (bx >> 2) & (CHv - 1), b = bx >> 2 >> __builtin_ctz(CHv);
    int tid = threadIdx.x;
    int d = dblk * 256 + tid;
    int row0 = b * Ll + chunk * CLv;

    float a[Ns], h[Ns];
    load_a(A_log, d, a);
    size_t base = ((size_t)b * CHv + chunk) * Dm + d;
    {
        const float4* Hp = (const float4*)(Hin + base * Ns);
        float4 h0 = Hp[0], h1 = Hp[1], h2 = Hp[2], h3 = Hp[3];
        h[0]=h0.x; h[1]=h0.y; h[2]=h0.z; h[3]=h0.w;
        h[4]=h1.x; h[5]=h1.y; h[6]=h1.z; h[7]=h1.w;
        h[8]=h2.x; h[9]=h2.y; h[10]=h2.z; h[11]=h2.w;
        h[12]=h3.x; h[13]=h3.y; h[14]=h3.z; h[15]=h3.w;
    }
    float Dval = Dp[d];

#pragma unroll 4
    for (int t = 0; t < CLv; ++t) {
        size_t row = (size_t)(row0 + t);
        float dl = delta[row * Dm + d];
        float xv = x[row * Dm + d];
        const float* bp = xp + row * Ee + Rr;
        float4 B0 = *(const float4*)(bp + 0),  B1 = *(const float4*)(bp + 4);
        float4 B2 = *(const float4*)(bp + 8),  B3 = *(const float4*)(bp + 12);
        float4 C0 = *(const float4*)(bp + 16), C1 = *(const float4*)(bp + 20);
        float4 C2 = *(const float4*)(bp + 24), C3 = *(const float4*)(bp + 28);
        float Bv[Ns] = {B0.x,B0.y,B0.z,B0.w, B1.x,B1.y,B1.z,B1.w,
                        B2.x,B2.y,B2.z,B2.w, B3.x,B3.y,B3.z,B3.w};
        float Cv[Ns] = {C0.x,C0.y,C0.z,C0.w, C1.x,C1.y,C1.z,C1.w,
                        C2.x,C2.y,C2.z,C2.w, C3.x,C3.y,C3.z,C3.w};
        float dx = dl * xv;
        float y = 0.f;
#pragma unroll
        for (int n = 0; n < Ns; ++n) {
            h[n] = fmaf(__expf(dl * a[n]), h[n], dx * Bv[n]);
            y = fmaf(h[n], Cv[n], y);
        }
        out[row * Dm + d] = fmaf(xv, Dval, y);
    }
}

extern "C" void kernel_launch(void* const* d_in, const int* in_sizes, int n_in,
                              void* d_out, int out_size, void* d_ws, size_t ws_size,
                              hipStream_t stream) {
    const float* x     = (const float*)d_in[0];
    const float* A_log = (const float*)d_in[1];
    const float* Dp    = (const float*)d_in[2];
    const float* xw    = (const float*)d_in[3];
    const float* dtw   = (const float*)d_in[4];
    const float* dtb   = (const float*)d_in[5];
    float* out = (float*)d_out;
    float* ws  = (float*)d_ws;

    // layout (floats):
    //   xp      : 393216
    //   delta   : 4194304
    //   S3 region (aliased):
    //     phase 1 : xp_part = 8 * 393216 = 3145728   [dead after k_prep]
    //     phase 4+: Ec (Bb*CH*Dm*Ns) | Sc (Bb*CH*Dm) | Hin (Bb*CH*Dm*Ns)
    float* xp      = ws;
    float* delta   = xp + 393216;
    float* S3      = delta + 4194304;
    float* xp_part = S3;

    k_xproj<<<dim3(512),  dim3(NTHR), 0, stream>>>(x, xw, xp_part);
    k_prep <<<dim3(384),  dim3(NTHR), 0, stream>>>(xp_part, xp);
    k_delta<<<dim3(1024), dim3(NTHR), 0, stream>>>(xp, dtw, dtb, delta);

    // CH=128 needs S3 = 2*(2*128*1024*16) + 2*128*1024 = 8,650,752 floats -> total 53 MB.
    // CH=64  needs S3 = 2*(2*64*1024*16)  + 2*64*1024  = 4,325,376 floats -> total 35.7 MB (proven fit).
    size_t need128 = (size_t)(393216 + 4194304 + 8650752) * 4;
    if (ws_size >= need128) {
        constexpr int CHv = 128;
        float* Ec  = S3;
        float* Sc  = Ec + (size_t)Bb*CHv*Dm*Ns;
        float* Hin = Sc + (size_t)Bb*CHv*Dm;
        k_scan_part<CHv><<<dim3(Bb*CHv*4), dim3(NTHR), 0, stream>>>(delta, x, xp, A_log, Ec, Sc);
        k_combine  <CHv><<<dim3(128),      dim3(NTHR), 0, stream>>>(Ec, Sc, A_log, Hin);
        k_scan_full<CHv><<<dim3(Bb*CHv*4), dim3(NTHR), 0, stream>>>(delta, x, xp, A_log, Dp, Hin, out);
    } else {
        constexpr int CHv = 64;
        float* Ec  = S3;
        float* Sc  = Ec + (size_t)Bb*CHv*Dm*Ns;
        float* Hin = Sc + (size_t)Bb*CHv*Dm;
        k_scan_part<CHv><<<dim3(Bb*CHv*4), dim3(NTHR), 0, stream>>>(delta, x, xp, A_log, Ec, Sc);
        k_combine  <CHv><<<dim3(128),      dim3(NTHR), 0, stream>>>(Ec, Sc, A_log, Hin);
        k_scan_full<CHv><<<dim3(Bb*CHv*4), dim3(NTHR), 0, stream>>>(delta, x, xp, A_log, Dp, Hin, out);
    }
}